// Round 7
// baseline (1565.547 us; speedup 1.0000x reference)
//
#include <hip/hip_runtime.h>
#include <cstdint>
#include <cstddef>

typedef unsigned long long u64;

#define NB 16
#define NC 64
#define NN 4096
#define NM 1024
#define NK 32

// ---------- DPP wave-reduction helpers (row_shr 1/2/4/8 + row_bcast 15/31) ----------

template <int C>
__device__ __forceinline__ float dppf(float x, float ident) {
  return __int_as_float(__builtin_amdgcn_update_dpp(
      __float_as_int(ident), __float_as_int(x), C, 0xf, 0xf, false));
}

template <int C>
__device__ __forceinline__ unsigned dppu(unsigned x, unsigned ident) {
  return (unsigned)__builtin_amdgcn_update_dpp(
      (int)ident, (int)x, C, 0xf, 0xf, false);
}

// full-wave (64-lane) float max; result broadcast via readlane(63)
__device__ __forceinline__ float wave_fmax(float x) {
  const float I = __int_as_float(0xff800000);  // -inf
  x = fmaxf(x, dppf<0x111>(x, I));
  x = fmaxf(x, dppf<0x112>(x, I));
  x = fmaxf(x, dppf<0x114>(x, I));
  x = fmaxf(x, dppf<0x118>(x, I));
  x = fmaxf(x, dppf<0x142>(x, I));  // row_bcast:15
  x = fmaxf(x, dppf<0x143>(x, I));  // row_bcast:31
  return __int_as_float(__builtin_amdgcn_readlane(__float_as_int(x), 63));
}

__device__ __forceinline__ float wave_fmin(float x) {
  const float I = __int_as_float(0x7f800000);  // +inf
  x = fminf(x, dppf<0x111>(x, I));
  x = fminf(x, dppf<0x112>(x, I));
  x = fminf(x, dppf<0x114>(x, I));
  x = fminf(x, dppf<0x118>(x, I));
  x = fminf(x, dppf<0x142>(x, I));
  x = fminf(x, dppf<0x143>(x, I));
  return __int_as_float(__builtin_amdgcn_readlane(__float_as_int(x), 63));
}

__device__ __forceinline__ unsigned wave_umin(unsigned x) {
  const unsigned I = 0xFFFFFFFFu;
  unsigned t;
  t = dppu<0x111>(x, I); x = x < t ? x : t;
  t = dppu<0x112>(x, I); x = x < t ? x : t;
  t = dppu<0x114>(x, I); x = x < t ? x : t;
  t = dppu<0x118>(x, I); x = x < t ? x : t;
  t = dppu<0x142>(x, I); x = x < t ? x : t;
  t = dppu<0x143>(x, I); x = x < t ? x : t;
  return (unsigned)__builtin_amdgcn_readlane((int)x, 63);
}

// ---------- kernel 0: pad W1 (64x67) -> W1p (64x68, zero col 67) ----------

__global__ __launch_bounds__(256) void pad_w1(const float* __restrict__ W1,
                                              float* __restrict__ W1p) {
  int g = blockIdx.x * 256 + threadIdx.x;
  if (g >= 64 * 68) return;
  int o = g / 68, c = g - o * 68;
  W1p[g] = (c < 67) ? W1[o * 67 + c] : 0.0f;
}

// ---------- kernel 1: feat (b,c,n) -> featT (b,n,c) ----------

__global__ __launch_bounds__(256) void transpose_feat(const float* __restrict__ feat,
                                                      float* __restrict__ featT) {
  int g = blockIdx.x * 256 + threadIdx.x;     // < NB*NN*NC
  int c = g & 63;
  int n = (g >> 6) & 4095;
  int b = g >> 18;
  featT[g] = feat[((size_t)(b * NC + c)) * NN + n];
}

// ---------- kernel 2: farthest point sampling (R4 version, verbatim) ----------

__global__ __launch_bounds__(256) void fps_kernel(const float* __restrict__ loc,
                                                  float* __restrict__ out_setloc) {
  __shared__ float4 red[2][4];
  const int b = blockIdx.x;
  const int tid = threadIdx.x;
  const int lane = tid & 63, wid = tid >> 6;
  const float* Lx = loc + (size_t)b * 3 * NN;
  const float* Ly = Lx + NN;
  const float* Lz = Ly + NN;
  const int p0 = tid * 16;
  float px[16], py[16], pz[16], dist[16];
#pragma unroll
  for (int j4 = 0; j4 < 4; ++j4) {
    float4 vx = *(const float4*)(Lx + p0 + 4 * j4);
    float4 vy = *(const float4*)(Ly + p0 + 4 * j4);
    float4 vz = *(const float4*)(Lz + p0 + 4 * j4);
    px[4 * j4] = vx.x; px[4 * j4 + 1] = vx.y; px[4 * j4 + 2] = vx.z; px[4 * j4 + 3] = vx.w;
    py[4 * j4] = vy.x; py[4 * j4 + 1] = vy.y; py[4 * j4 + 2] = vy.z; py[4 * j4 + 3] = vy.w;
    pz[4 * j4] = vz.x; pz[4 * j4 + 1] = vz.y; pz[4 * j4 + 2] = vz.z; pz[4 * j4 + 3] = vz.w;
  }
#pragma unroll
  for (int j = 0; j < 16; ++j) dist[j] = __int_as_float(0x7f800000);
  if (tid == 0) red[1][0] = make_float4(0.0f, px[0], py[0], pz[0]);  // bootstrap: point 0
  __syncthreads();
  float4 boot = red[1][0];
  float sx = boot.y, sy = boot.z, sz = boot.w;

  // register shift-queue of captured winners (slot s captured by tid == s%256)
  float w0x = 0, w0y = 0, w0z = 0, w1x = 0, w1y = 0, w1z = 0;
  float w2x = 0, w2y = 0, w2z = 0, w3x = 0, w3y = 0, w3z = 0;
  if (tid == 0) { w0x = sx; w0y = sy; w0z = sz; }  // slot 0 = point 0

  for (int s = 0; s < NM - 1; ++s) {  // compute winners for slots 1..1023
    float bd = -1.0f, bx = 0.0f, by = 0.0f, bz = 0.0f;
#pragma unroll
    for (int j = 0; j < 16; ++j) {
      // match numpy: plain mul, left-assoc adds, no contraction
      float dx = __fsub_rn(px[j], sx);
      float dy = __fsub_rn(py[j], sy);
      float dz = __fsub_rn(pz[j], sz);
      float d2 = __fadd_rn(__fadd_rn(__fmul_rn(dx, dx), __fmul_rn(dy, dy)), __fmul_rn(dz, dz));
      float nd = fminf(dist[j], d2);
      dist[j] = nd;
      bool g = nd > bd;  // strict > keeps lowest j (= lowest index)
      bd = g ? nd : bd;
      bx = g ? px[j] : bx;
      by = g ? py[j] : by;
      bz = g ? pz[j] : bz;
    }
    // wave argmax: DPP value max, lowest tied lane (= lowest index) writes cand
    float wmax = wave_fmax(bd);
    u64 m = __ballot(bd == wmax);
    if (lane == __ffsll((long long)m) - 1) red[s & 1][wid] = make_float4(bd, bx, by, bz);
    __syncthreads();
    // 4-way serial argmax, ascending wid + strict > == global first-max
    float4 c0 = red[s & 1][0], c1 = red[s & 1][1], c2 = red[s & 1][2], c3 = red[s & 1][3];
    float bdd = c0.x; sx = c0.y; sy = c0.z; sz = c0.w;
    bool g1 = c1.x > bdd; bdd = g1 ? c1.x : bdd; sx = g1 ? c1.y : sx; sy = g1 ? c1.z : sy; sz = g1 ? c1.w : sz;
    bool g2 = c2.x > bdd; bdd = g2 ? c2.x : bdd; sx = g2 ? c2.y : sx; sy = g2 ? c2.z : sy; sz = g2 ? c2.w : sz;
    bool g3 = c3.x > bdd; bdd = g3 ? c3.x : bdd; sx = g3 ? c3.y : sx; sy = g3 ? c3.z : sy; sz = g3 ? c3.w : sz;
    // capture slot s+1 into the shift queue (static indices only)
    if (tid == ((s + 1) & 255)) {
      w3x = w2x; w3y = w2y; w3z = w2z;
      w2x = w1x; w2y = w1y; w2z = w1z;
      w1x = w0x; w1y = w0y; w1z = w0z;
      w0x = sx;  w0y = sy;  w0z = sz;
    }
  }
  // thread t holds slots t(w3), t+256(w2), t+512(w1), t+768(w0); coalesced write
  float* Ox = out_setloc + (b * 3 + 0) * NM;
  float* Oy = out_setloc + (b * 3 + 1) * NM;
  float* Oz = out_setloc + (b * 3 + 2) * NM;
  Ox[tid] = w3x;       Oy[tid] = w3y;       Oz[tid] = w3z;
  Ox[tid + 256] = w2x; Oy[tid + 256] = w2y; Oz[tid + 256] = w2z;
  Ox[tid + 512] = w1x; Oy[tid + 512] = w1y; Oz[tid + 512] = w1z;
  Ox[tid + 768] = w0x; Oy[tid + 768] = w0y; Oz[tid + 768] = w0z;
}

// ---------- kernel 3: kNN (one wave per query, DPP-min extraction) ----------

__global__ __launch_bounds__(256) void knn_kernel(const float* __restrict__ loc,
                                                  const float* __restrict__ setloc,
                                                  int* __restrict__ ws_knn) {
  const int wq = blockIdx.x * 4 + (threadIdx.x >> 6);  // query id, < NB*NM
  const int lane = threadIdx.x & 63;
  const int b = wq >> 10, mq = wq & 1023;
  const float* Sb = setloc + (size_t)b * 3 * NM;
  float xs = Sb[mq], ys = Sb[NM + mq], zs = Sb[2 * NM + mq];
  float sqs = __fadd_rn(__fadd_rn(__fmul_rn(xs, xs), __fmul_rn(ys, ys)), __fmul_rn(zs, zs));
  const float* Lx = loc + (size_t)b * 3 * NN;
  const float* Ly = Lx + NN;
  const float* Lz = Ly + NN;
  const float INF = __int_as_float(0x7f800000);

  // per-lane two smallest (value, index); lane owns points p = j*64+lane
  float k1 = INF, k2 = INF;
  unsigned i1 = 0xFFFFFFFFu, i2 = 0xFFFFFFFFu;
#pragma unroll 8
  for (int j = 0; j < 64; ++j) {
    int p = j * 64 + lane;
    float x = Lx[p], y = Ly[p], z = Lz[p];
    float sql = __fadd_rn(__fadd_rn(__fmul_rn(x, x), __fmul_rn(y, y)), __fmul_rn(z, z));
    float cr  = __fadd_rn(__fadd_rn(__fmul_rn(xs, x), __fmul_rn(ys, y)), __fmul_rn(zs, z));
    float d2  = __fsub_rn(__fadd_rn(sqs, sql), __fmul_rn(2.0f, cr));
    if (d2 < k1)      { k2 = k1; i2 = i1; k1 = d2; i1 = (unsigned)p; }
    else if (d2 < k2) { k2 = d2; i2 = (unsigned)p; }
  }

  u64 used = 0;        // per-lane mask of extracted j-slots
  unsigned keep = 0;   // lane s holds round-s winner
  for (int s = 0; s < NK; ++s) {
    float wmin = wave_fmin(k1);
    u64 mask = __ballot(k1 == wmin);
    int ownerLane;
    if (__popcll(mask) > 1) {
      // exact tie-break: smallest global index among tied lanes
      unsigned cand = (k1 == wmin) ? i1 : 0xFFFFFFFFu;
      unsigned minp = wave_umin(cand);
      u64 m2 = __ballot(k1 == wmin && i1 == minp);
      ownerLane = __ffsll((long long)m2) - 1;
    } else {
      ownerLane = __ffsll((long long)mask) - 1;
    }
    unsigned widx = (unsigned)__builtin_amdgcn_readlane((int)i1, ownerLane);
    if (lane == s) keep = widx;
    if (lane == ownerLane) {
      used |= 1ull << (i1 >> 6);
      k1 = k2; i1 = i2;
      k2 = INF; i2 = 0xFFFFFFFFu;
      if (__float_as_uint(k1) == 0x7f800000u) {
        // rare refill: recompute this lane's remaining distances (L2-hot loc)
#pragma unroll 8
        for (int j = 0; j < 64; ++j) {
          if (!((used >> j) & 1ull)) {
            int p = j * 64 + lane;
            float x = Lx[p], y = Ly[p], z = Lz[p];
            float sql = __fadd_rn(__fadd_rn(__fmul_rn(x, x), __fmul_rn(y, y)), __fmul_rn(z, z));
            float cr  = __fadd_rn(__fadd_rn(__fmul_rn(xs, x), __fmul_rn(ys, y)), __fmul_rn(zs, z));
            float d2  = __fsub_rn(__fadd_rn(sqs, sql), __fmul_rn(2.0f, cr));
            if (d2 < k1)      { k2 = k1; i2 = i1; k1 = d2; i1 = (unsigned)p; }
            else if (d2 < k2) { k2 = d2; i2 = (unsigned)p; }
          }
        }
      }
    }
  }
  if (lane < NK) ws_knn[(size_t)wq * NK + lane] = (int)keep;
}

// ---------- kernel 4: fused gather + 3-layer MLP + maxpool ----------
// NAMED-SCALAR version: x/y1/y2 as 196 named floats (no arrays -> no alloca
// -> no scratch; SROA-before-unroll can't demote named scalars). Weights
// staged per-layer in one 32KB LDS buffer (broadcast reads). launch_bounds
// (256,1) allows the ~200-250 VGPR allocation (2 waves/SIMD).

#define LD4(p) (*(const float4*)(p))
#define FMA4(ACC, W, XA, XB, XC, XD) { \
    ACC = fmaf(W.x, XA, ACC); ACC = fmaf(W.y, XB, ACC); \
    ACC = fmaf(W.z, XC, ACC); ACC = fmaf(W.w, XD, ACC); }
// 8 output rows x 4 input channels, weights from LDS (row stride S floats)
#define ROWS8(CH, S, XA, XB, XC, XD) { \
    float4 q0 = LD4(wr + 0*(S) + 4*(CH)), q1 = LD4(wr + 1*(S) + 4*(CH)); \
    float4 q2 = LD4(wr + 2*(S) + 4*(CH)), q3 = LD4(wr + 3*(S) + 4*(CH)); \
    float4 q4 = LD4(wr + 4*(S) + 4*(CH)), q5 = LD4(wr + 5*(S) + 4*(CH)); \
    float4 q6 = LD4(wr + 6*(S) + 4*(CH)), q7 = LD4(wr + 7*(S) + 4*(CH)); \
    FMA4(a0, q0, XA, XB, XC, XD) FMA4(a1, q1, XA, XB, XC, XD) \
    FMA4(a2, q2, XA, XB, XC, XD) FMA4(a3, q3, XA, XB, XC, XD) \
    FMA4(a4, q4, XA, XB, XC, XD) FMA4(a5, q5, XA, XB, XC, XD) \
    FMA4(a6, q6, XA, XB, XC, XD) FMA4(a7, q7, XA, XB, XC, XD) }
#define RELU8() { a0=fmaxf(a0,0.f); a1=fmaxf(a1,0.f); a2=fmaxf(a2,0.f); a3=fmaxf(a3,0.f); \
                  a4=fmaxf(a4,0.f); a5=fmaxf(a5,0.f); a6=fmaxf(a6,0.f); a7=fmaxf(a7,0.f); }
#define SC(V0,V1,V2,V3,V4,V5,V6,V7) { V0=a0;V1=a1;V2=a2;V3=a3;V4=a4;V5=a5;V6=a6;V7=a7; }
#define BFLY(a) { a = fmaxf(a, __shfl_xor(a, 16, 64)); a = fmaxf(a, __shfl_xor(a, 8, 64)); \
                  a = fmaxf(a, __shfl_xor(a, 4, 64));  a = fmaxf(a, __shfl_xor(a, 2, 64)); \
                  a = fmaxf(a, __shfl_xor(a, 1, 64)); }
#define LDX(I, V0, V1, V2, V3) { float4 v = LD4(fx + 4*(I)); V0=v.x; V1=v.y; V2=v.z; V3=v.w; }
#define STAGE(DST4, SRC4, N4) { \
    for (int t = threadIdx.x; t < (N4); t += 256) \
      ((float4*)(DST4))[t] = ((const float4*)(SRC4))[t]; }

__global__ __launch_bounds__(256, 1) void mlp_kernel(
    const float* __restrict__ featT, const float* __restrict__ loc,
    const float* __restrict__ setloc, const int* __restrict__ ws_knn,
    const float* __restrict__ W1p, const float* __restrict__ b1,
    const float* __restrict__ W2, const float* __restrict__ b2,
    const float* __restrict__ W3, const float* __restrict__ b3,
    float* __restrict__ out) {
  __shared__ __align__(16) float wlds[8192];  // 32KB: max(W1p 4352, W2 4096, W3 8192)
  const int lane = threadIdx.x & 63;
  const int wix = blockIdx.x * 4 + (threadIdx.x >> 6);  // wave id, < 8192
  const int q = wix * 2 + (lane >> 5);                  // query id, < 16384
  const int col = lane & 31;                            // neighbor slot (k)
  const int b = q >> 10, mq = q & 1023;
  const int nk = ws_knn[(size_t)q * NK + col];

  // gather input column: 64 feat channels + 3 rel-loc + zero pad, named scalars
  const float* fx = featT + ((size_t)(b * NN + nk)) * 64;
  float X0,X1,X2,X3,X4,X5,X6,X7,X8,X9,X10,X11,X12,X13,X14,X15;
  float X16,X17,X18,X19,X20,X21,X22,X23,X24,X25,X26,X27,X28,X29,X30,X31;
  float X32,X33,X34,X35,X36,X37,X38,X39,X40,X41,X42,X43,X44,X45,X46,X47;
  float X48,X49,X50,X51,X52,X53,X54,X55,X56,X57,X58,X59,X60,X61,X62,X63;
  float X64,X65,X66,X67;
  LDX(0,  X0,  X1,  X2,  X3)  LDX(1,  X4,  X5,  X6,  X7)
  LDX(2,  X8,  X9,  X10, X11) LDX(3,  X12, X13, X14, X15)
  LDX(4,  X16, X17, X18, X19) LDX(5,  X20, X21, X22, X23)
  LDX(6,  X24, X25, X26, X27) LDX(7,  X28, X29, X30, X31)
  LDX(8,  X32, X33, X34, X35) LDX(9,  X36, X37, X38, X39)
  LDX(10, X40, X41, X42, X43) LDX(11, X44, X45, X46, X47)
  LDX(12, X48, X49, X50, X51) LDX(13, X52, X53, X54, X55)
  LDX(14, X56, X57, X58, X59) LDX(15, X60, X61, X62, X63)
  {
    const float* Lb = loc + (size_t)b * 3 * NN;
    const float* Sb = setloc + (size_t)b * 3 * NM;
    X64 = Lb[nk] - Sb[mq];
    X65 = Lb[NN + nk] - Sb[NM + mq];
    X66 = Lb[2 * NN + nk] - Sb[2 * NM + mq];
    X67 = 0.0f;  // pairs with W1p zero column
  }

  float A0,A1,A2,A3,A4,A5,A6,A7,A8,A9,A10,A11,A12,A13,A14,A15;
  float A16,A17,A18,A19,A20,A21,A22,A23,A24,A25,A26,A27,A28,A29,A30,A31;
  float A32,A33,A34,A35,A36,A37,A38,A39,A40,A41,A42,A43,A44,A45,A46,A47;
  float A48,A49,A50,A51,A52,A53,A54,A55,A56,A57,A58,A59,A60,A61,A62,A63;

  // ---- layer 1: 68 -> 64 (padded), weights in LDS ----
  STAGE(wlds, W1p, 1088)   // 4352 f32
  __syncthreads();
#pragma unroll 1
  for (int ob = 0; ob < 8; ++ob) {
    const float* wr = wlds + ob * 544;
    const float* bb = b1 + ob * 8;
    float a0 = bb[0], a1 = bb[1], a2 = bb[2], a3 = bb[3];
    float a4 = bb[4], a5 = bb[5], a6 = bb[6], a7 = bb[7];
    ROWS8(0,  68, X0,  X1,  X2,  X3)  ROWS8(1,  68, X4,  X5,  X6,  X7)
    ROWS8(2,  68, X8,  X9,  X10, X11) ROWS8(3,  68, X12, X13, X14, X15)
    ROWS8(4,  68, X16, X17, X18, X19) ROWS8(5,  68, X20, X21, X22, X23)
    ROWS8(6,  68, X24, X25, X26, X27) ROWS8(7,  68, X28, X29, X30, X31)
    ROWS8(8,  68, X32, X33, X34, X35) ROWS8(9,  68, X36, X37, X38, X39)
    ROWS8(10, 68, X40, X41, X42, X43) ROWS8(11, 68, X44, X45, X46, X47)
    ROWS8(12, 68, X48, X49, X50, X51) ROWS8(13, 68, X52, X53, X54, X55)
    ROWS8(14, 68, X56, X57, X58, X59) ROWS8(15, 68, X60, X61, X62, X63)
    ROWS8(16, 68, X64, X65, X66, X67)
    RELU8();
    switch (ob) {
      case 0: SC(A0,A1,A2,A3,A4,A5,A6,A7) break;
      case 1: SC(A8,A9,A10,A11,A12,A13,A14,A15) break;
      case 2: SC(A16,A17,A18,A19,A20,A21,A22,A23) break;
      case 3: SC(A24,A25,A26,A27,A28,A29,A30,A31) break;
      case 4: SC(A32,A33,A34,A35,A36,A37,A38,A39) break;
      case 5: SC(A40,A41,A42,A43,A44,A45,A46,A47) break;
      case 6: SC(A48,A49,A50,A51,A52,A53,A54,A55) break;
      case 7: SC(A56,A57,A58,A59,A60,A61,A62,A63) break;
    }
  }
  __syncthreads();

  // ---- layer 2: 64 -> 64 ----
  STAGE(wlds, W2, 1024)    // 4096 f32
  __syncthreads();
  float B0,B1,B2,B3,B4,B5,B6,B7,B8,B9,B10,B11,B12,B13,B14,B15;
  float B16,B17,B18,B19,B20,B21,B22,B23,B24,B25,B26,B27,B28,B29,B30,B31;
  float B32,B33,B34,B35,B36,B37,B38,B39,B40,B41,B42,B43,B44,B45,B46,B47;
  float B48,B49,B50,B51,B52,B53,B54,B55,B56,B57,B58,B59,B60,B61,B62,B63;
#pragma unroll 1
  for (int ob = 0; ob < 8; ++ob) {
    const float* wr = wlds + ob * 512;
    const float* bb = b2 + ob * 8;
    float a0 = bb[0], a1 = bb[1], a2 = bb[2], a3 = bb[3];
    float a4 = bb[4], a5 = bb[5], a6 = bb[6], a7 = bb[7];
    ROWS8(0,  64, A0,  A1,  A2,  A3)  ROWS8(1,  64, A4,  A5,  A6,  A7)
    ROWS8(2,  64, A8,  A9,  A10, A11) ROWS8(3,  64, A12, A13, A14, A15)
    ROWS8(4,  64, A16, A17, A18, A19) ROWS8(5,  64, A20, A21, A22, A23)
    ROWS8(6,  64, A24, A25, A26, A27) ROWS8(7,  64, A28, A29, A30, A31)
    ROWS8(8,  64, A32, A33, A34, A35) ROWS8(9,  64, A36, A37, A38, A39)
    ROWS8(10, 64, A40, A41, A42, A43) ROWS8(11, 64, A44, A45, A46, A47)
    ROWS8(12, 64, A48, A49, A50, A51) ROWS8(13, 64, A52, A53, A54, A55)
    ROWS8(14, 64, A56, A57, A58, A59) ROWS8(15, 64, A60, A61, A62, A63)
    RELU8();
    switch (ob) {
      case 0: SC(B0,B1,B2,B3,B4,B5,B6,B7) break;
      case 1: SC(B8,B9,B10,B11,B12,B13,B14,B15) break;
      case 2: SC(B16,B17,B18,B19,B20,B21,B22,B23) break;
      case 3: SC(B24,B25,B26,B27,B28,B29,B30,B31) break;
      case 4: SC(B32,B33,B34,B35,B36,B37,B38,B39) break;
      case 5: SC(B40,B41,B42,B43,B44,B45,B46,B47) break;
      case 6: SC(B48,B49,B50,B51,B52,B53,B54,B55) break;
      case 7: SC(B56,B57,B58,B59,B60,B61,B62,B63) break;
    }
  }
  __syncthreads();

  // ---- layer 3: 64 -> 128, fused maxpool over the 32 columns + store ----
  STAGE(wlds, W3, 2048)    // 8192 f32
  __syncthreads();
#pragma unroll 1
  for (int ob = 0; ob < 16; ++ob) {
    const float* wr = wlds + ob * 512;
    const float* bb = b3 + ob * 8;
    float a0 = bb[0], a1 = bb[1], a2 = bb[2], a3 = bb[3];
    float a4 = bb[4], a5 = bb[5], a6 = bb[6], a7 = bb[7];
    ROWS8(0,  64, B0,  B1,  B2,  B3)  ROWS8(1,  64, B4,  B5,  B6,  B7)
    ROWS8(2,  64, B8,  B9,  B10, B11) ROWS8(3,  64, B12, B13, B14, B15)
    ROWS8(4,  64, B16, B17, B18, B19) ROWS8(5,  64, B20, B21, B22, B23)
    ROWS8(6,  64, B24, B25, B26, B27) ROWS8(7,  64, B28, B29, B30, B31)
    ROWS8(8,  64, B32, B33, B34, B35) ROWS8(9,  64, B36, B37, B38, B39)
    ROWS8(10, 64, B40, B41, B42, B43) ROWS8(11, 64, B44, B45, B46, B47)
    ROWS8(12, 64, B48, B49, B50, B51) ROWS8(13, 64, B52, B53, B54, B55)
    ROWS8(14, 64, B56, B57, B58, B59) ROWS8(15, 64, B60, B61, B62, B63)
    RELU8();
    BFLY(a0); BFLY(a1); BFLY(a2); BFLY(a3);
    BFLY(a4); BFLY(a5); BFLY(a6); BFLY(a7);
    if (col == 0) {
      float* op = out + ((size_t)b * 128 + ob * 8) * NM + mq;
      op[0] = a0;       op[NM] = a1;     op[2 * NM] = a2; op[3 * NM] = a3;
      op[4 * NM] = a4;  op[5 * NM] = a5; op[6 * NM] = a6; op[7 * NM] = a7;
    }
  }
}

// ---------- launch ----------

extern "C" void kernel_launch(void* const* d_in, const int* in_sizes, int n_in,
                              void* d_out, int out_size, void* d_ws, size_t ws_size,
                              hipStream_t stream) {
  (void)in_sizes; (void)n_in; (void)out_size; (void)ws_size;
  const float* feat = (const float*)d_in[0];
  const float* loc  = (const float*)d_in[1];
  const float* W1   = (const float*)d_in[2];
  const float* b1   = (const float*)d_in[3];
  const float* W2   = (const float*)d_in[4];
  const float* b2   = (const float*)d_in[5];
  const float* W3   = (const float*)d_in[6];
  const float* b3   = (const float*)d_in[7];
  float* out = (float*)d_out;

  char* ws = (char*)d_ws;
  int*   ws_knn   = (int*)ws;                           // 16*1024*32 i32 = 2 MB
  float* ws_featT = (float*)(ws + 2097152);             // 16*4096*64 f32 = 16.75 MB
  float* ws_w1p   = (float*)(ws + 2097152 + 16777216);  // 64*68 f32

  float* out_setfeat = out;                          // (16,128,1024)
  float* out_setloc  = out + (size_t)NB * 128 * NM;  // (16,3,1024)

  pad_w1<<<dim3(17), dim3(256), 0, stream>>>(W1, ws_w1p);
  transpose_feat<<<dim3((NB * NN * NC) / 256), dim3(256), 0, stream>>>(feat, ws_featT);
  fps_kernel<<<dim3(NB), dim3(256), 0, stream>>>(loc, out_setloc);
  knn_kernel<<<dim3((NB * NM) / 4), dim3(256), 0, stream>>>(loc, out_setloc, ws_knn);
  mlp_kernel<<<dim3((NB * NM) / 8), dim3(256), 0, stream>>>(
      ws_featT, loc, out_setloc, ws_knn, ws_w1p, b1, W2, b2, W3, b3, out_setfeat);
}